// Round 1
// baseline (253.374 us; speedup 1.0000x reference)
//
#include <hip/hip_runtime.h>

#define F16 _Float16
typedef _Float16 f16x8 __attribute__((ext_vector_type(8)));
typedef _Float16 f16x4 __attribute__((ext_vector_type(4)));
typedef float f32x4 __attribute__((ext_vector_type(4)));

#define NB    4
#define CIN   512
#define NN    4096
#define KCH   256
#define OCH   512
#define BNEPS 1e-5f

// workspace layout (bytes)
#define XT_OFF   0u                    // [B][N][C]   f16  16 MB
#define KQT_OFF  (16u*1024*1024)       // [B][N][K]   f16   8 MB
#define VG_OFF   (24u*1024*1024)       // [B][V][N]   f16   8 MB
#define CTX_OFF  (32u*1024*1024)       // [B][N][V]   f16   8 MB

// ---------------------------------------------------------------- transpose
// x [B][C][N] f32  ->  xT [B][N][C] f16
__global__ __launch_bounds__(256) void k_transpose(const float* __restrict__ x,
                                                   F16* __restrict__ xT) {
    __shared__ float tile[64][65];
    int b = blockIdx.z, n0 = blockIdx.y * 64, c0 = blockIdx.x * 64;
    int t = threadIdx.x;
    const float* xb = x + (size_t)b * CIN * NN;
#pragma unroll
    for (int i = 0; i < 4; i++) {
        int c = (t >> 4) + i * 16;
        int n = (t & 15) * 4;
        float4 v = *(const float4*)&xb[(size_t)(c0 + c) * NN + n0 + n];
        tile[c][n + 0] = v.x; tile[c][n + 1] = v.y;
        tile[c][n + 2] = v.z; tile[c][n + 3] = v.w;
    }
    __syncthreads();
    F16* xTb = xT + (size_t)b * NN * CIN;
#pragma unroll
    for (int i = 0; i < 4; i++) {
        int n = (t >> 4) + i * 16;
        int c = (t & 15) * 4;
        f16x4 o;
        o[0] = (F16)tile[c + 0][n]; o[1] = (F16)tile[c + 1][n];
        o[2] = (F16)tile[c + 2][n]; o[3] = (F16)tile[c + 3][n];
        *(f16x4*)&xTb[(size_t)(n0 + n) * CIN + c0 + c] = o;
    }
}

// ---------------------------------------------------------------- K/V GEMM
// D[ch][n] = sum_c W[ch][c] * x[c][n], ch<256 -> BN+ReLU -> KQt[n][ch]
//                                      ch>=256 -> +bias  -> Vg[v][n]
__global__ __launch_bounds__(256) void k_kv_gemm(
    const F16* __restrict__ xT,
    const float* __restrict__ key_w, const float* __restrict__ key_b,
    const float* __restrict__ gamma, const float* __restrict__ beta,
    const float* __restrict__ mean,  const float* __restrict__ var,
    const float* __restrict__ value_w, const float* __restrict__ value_b,
    F16* __restrict__ KQt, F16* __restrict__ Vg) {
    __shared__ F16 Al[128][40];
    __shared__ F16 Bl[128][40];
    int b = blockIdx.z;
    int m0 = blockIdx.y * 128;
    int n0 = blockIdx.x * 128;
    int t = threadIdx.x, w = t >> 6, l = t & 63;
    int wr = w >> 1, wc = w & 1;
    int lr = l >> 4, lc = l & 15;
    f32x4 acc[4][4];
    const f32x4 fz = {0.f, 0.f, 0.f, 0.f};
#pragma unroll
    for (int i = 0; i < 4; i++)
#pragma unroll
        for (int j = 0; j < 4; j++) acc[i][j] = fz;
    const F16* xb = xT + (size_t)b * NN * CIN;

    for (int kt = 0; kt < CIN / 32; kt++) {
        int c0 = kt * 32;
        __syncthreads();
        // stage A (weights f32 -> f16), 128 rows x 32 cols
#pragma unroll
        for (int p = 0; p < 4; p++) {
            int row = (t >> 3) + p * 32;
            int cc = (t & 7) * 4;
            int rg = m0 + row;
            const float* src = (rg < 256) ? (key_w + (size_t)rg * CIN)
                                          : (value_w + (size_t)(rg - 256) * CIN);
            float4 v = *(const float4*)&src[c0 + cc];
            f16x4 h; h[0] = (F16)v.x; h[1] = (F16)v.y; h[2] = (F16)v.z; h[3] = (F16)v.w;
            *(f16x4*)&Al[row][cc] = h;
        }
        // stage B (xT f16), 128 rows x 32 cols
#pragma unroll
        for (int p = 0; p < 2; p++) {
            int row = (t >> 2) + p * 64;
            int cc = (t & 3) * 8;
            *(int4*)&Bl[row][cc] = *(const int4*)&xb[(size_t)(n0 + row) * CIN + c0 + cc];
        }
        __syncthreads();
        f16x8 a[4];
#pragma unroll
        for (int fi = 0; fi < 4; fi++)
            a[fi] = *(f16x8*)&Al[wr * 64 + fi * 16 + lc][lr * 8];
#pragma unroll
        for (int fj = 0; fj < 4; fj++) {
            f16x8 bb = *(f16x8*)&Bl[wc * 64 + fj * 16 + lc][lr * 8];
#pragma unroll
            for (int fi = 0; fi < 4; fi++)
                acc[fi][fj] = __builtin_amdgcn_mfma_f32_16x16x32_f16(a[fi], bb, acc[fi][fj], 0, 0, 0);
        }
    }

    if (m0 < 256) {
#pragma unroll
        for (int fi = 0; fi < 4; fi++) {
            int ch0 = m0 + wr * 64 + fi * 16 + lr * 4;
            float invs[4], mns[4], bts[4], kbs[4];
#pragma unroll
            for (int r = 0; r < 4; r++) {
                int ch = ch0 + r;
                invs[r] = gamma[ch] * rsqrtf(var[ch] + BNEPS);
                mns[r] = mean[ch]; bts[r] = beta[ch]; kbs[r] = key_b[ch];
            }
#pragma unroll
            for (int fj = 0; fj < 4; fj++) {
                int n = n0 + wc * 64 + fj * 16 + lc;
                f16x4 o;
#pragma unroll
                for (int r = 0; r < 4; r++) {
                    float v = (acc[fi][fj][r] + kbs[r] - mns[r]) * invs[r] + bts[r];
                    v = fmaxf(v, 0.0f);
                    o[r] = (F16)v;
                }
                *(f16x4*)&KQt[((size_t)b * NN + n) * KCH + ch0] = o;
            }
        }
    } else {
#pragma unroll
        for (int fi = 0; fi < 4; fi++) {
            int v0 = m0 - 256 + wr * 64 + fi * 16 + lr * 4;
#pragma unroll
            for (int fj = 0; fj < 4; fj++) {
                int n = n0 + wc * 64 + fj * 16 + lc;
#pragma unroll
                for (int r = 0; r < 4; r++) {
                    float vv = acc[fi][fj][r] + value_b[v0 + r];
                    Vg[((size_t)b * KCH + v0 + r) * NN + n] = (F16)vv;
                }
            }
        }
    }
}

// ---------------------------------------------------------------- flash attention
// per block: batch b, 64 query rows; loop over 64-wide key/value tiles
__global__ __launch_bounds__(256) void k_flash(const F16* __restrict__ KQt,
                                               const F16* __restrict__ Vg,
                                               F16* __restrict__ ctxT) {
    __shared__ F16 Ql[64 * 264];
    __shared__ F16 Kl[64 * 264];
    __shared__ F16 Vl[256 * 72];
    __shared__ F16 Pl[4][16 * 72];
    int q = blockIdx.x;
    int xcd = q & 7;
    int b = xcd >> 1;                       // batch pinned to an XCD pair (L2 locality)
    int nt = (xcd & 1) * 32 + (q >> 3);
    int n0 = nt * 64;
    int t = threadIdx.x, w = t >> 6, l = t & 63;
    int lr = l >> 4, lc = l & 15;
    const F16* kqb = KQt + (size_t)b * NN * KCH;
    const F16* vgb = Vg + (size_t)b * KCH * NN;

    // load Q tile [64][256] -> padded LDS [64][264]
#pragma unroll
    for (int p = 0; p < 8; p++) {
        int row = (t >> 5) + p * 8;
        int off = (t & 31) * 8;
        *(int4*)&Ql[row * 264 + off] = *(const int4*)&kqb[(size_t)(n0 + row) * KCH + off];
    }

    f32x4 acc[16];
    const f32x4 fz = {0.f, 0.f, 0.f, 0.f};
#pragma unroll
    for (int i = 0; i < 16; i++) acc[i] = fz;
    float m_run[4] = {-1e30f, -1e30f, -1e30f, -1e30f};
    float l_run[4] = {0.f, 0.f, 0.f, 0.f};

    for (int mt = 0; mt < 64; mt++) {
        int m0 = mt * 64;
        __syncthreads();
        // stage K tile [64][256]
#pragma unroll
        for (int p = 0; p < 8; p++) {
            int row = (t >> 5) + p * 8;
            int off = (t & 31) * 8;
            *(int4*)&Kl[row * 264 + off] = *(const int4*)&kqb[(size_t)(m0 + row) * KCH + off];
        }
        // stage V tile [256 v][64 m]
#pragma unroll
        for (int p = 0; p < 8; p++) {
            int vv = (t >> 3) + p * 32;
            int off = (t & 7) * 8;
            *(int4*)&Vl[vv * 72 + off] = *(const int4*)&vgb[(size_t)vv * NN + m0 + off];
        }
        __syncthreads();

        // S = Q^T K  (per wave: 16 rows x 64 cols, contraction 256)
        f32x4 s[4];
#pragma unroll
        for (int f = 0; f < 4; f++) s[f] = fz;
#pragma unroll
        for (int ks = 0; ks < 8; ks++) {
            f16x8 a = *(f16x8*)&Ql[(w * 16 + lc) * 264 + ks * 32 + lr * 8];
#pragma unroll
            for (int f = 0; f < 4; f++) {
                f16x8 bb = *(f16x8*)&Kl[(f * 16 + lc) * 264 + ks * 32 + lr * 8];
                s[f] = __builtin_amdgcn_mfma_f32_16x16x32_f16(a, bb, s[f], 0, 0, 0);
            }
        }

        // online softmax (rows live across the 16-lane group)
        const float scale = 0.0625f;
#pragma unroll
        for (int r = 0; r < 4; r++) {
            float mx = fmaxf(fmaxf(s[0][r], s[1][r]), fmaxf(s[2][r], s[3][r])) * scale;
#pragma unroll
            for (int off = 1; off < 16; off <<= 1) mx = fmaxf(mx, __shfl_xor(mx, off, 64));
            float mnew = fmaxf(m_run[r], mx);
            float corr = __expf(m_run[r] - mnew);
            m_run[r] = mnew;
            float ps = 0.0f;
#pragma unroll
            for (int f = 0; f < 4; f++) {
                float p = __expf(s[f][r] * scale - mnew);
                ps += p;
                Pl[w][(lr * 4 + r) * 72 + f * 16 + lc] = (F16)p;
            }
#pragma unroll
            for (int off = 1; off < 16; off <<= 1) ps += __shfl_xor(ps, off, 64);
            l_run[r] = l_run[r] * corr + ps;
#pragma unroll
            for (int fv = 0; fv < 16; fv++) acc[fv][r] *= corr;
        }
        __syncthreads();

        // ctx += P V^T   (per wave: 16 rows x 256 v, contraction 64)
#pragma unroll
        for (int ks = 0; ks < 2; ks++) {
            f16x8 a = *(f16x8*)&Pl[w][lc * 72 + ks * 32 + lr * 8];
#pragma unroll
            for (int fv = 0; fv < 16; fv++) {
                f16x8 bb = *(f16x8*)&Vl[(fv * 16 + lc) * 72 + ks * 32 + lr * 8];
                acc[fv] = __builtin_amdgcn_mfma_f32_16x16x32_f16(a, bb, acc[fv], 0, 0, 0);
            }
        }
    }

    // epilogue: ctxT[n][v] = acc / l_run
    F16* cb = ctxT + (size_t)b * NN * KCH;
#pragma unroll
    for (int r = 0; r < 4; r++) {
        int n = n0 + w * 16 + lr * 4 + r;
        float inv = 1.0f / l_run[r];
#pragma unroll
        for (int fv = 0; fv < 16; fv++)
            cb[(size_t)n * KCH + fv * 16 + lc] = (F16)(acc[fv][r] * inv);
    }
}

// ---------------------------------------------------------------- out GEMM
// out[o][n] = sum_v w_w[o][v] * ctx[v][n] + w_b[o]   (f32 out)
__global__ __launch_bounds__(256) void k_out_gemm(const F16* __restrict__ ctxT,
                                                  const float* __restrict__ w_w,
                                                  const float* __restrict__ w_b,
                                                  float* __restrict__ out) {
    __shared__ F16 Al[128][40];
    __shared__ F16 Bl[128][40];
    int b = blockIdx.z;
    int m0 = blockIdx.y * 128;
    int n0 = blockIdx.x * 128;
    int t = threadIdx.x, w = t >> 6, l = t & 63;
    int wr = w >> 1, wc = w & 1;
    int lr = l >> 4, lc = l & 15;
    f32x4 acc[4][4];
    const f32x4 fz = {0.f, 0.f, 0.f, 0.f};
#pragma unroll
    for (int i = 0; i < 4; i++)
#pragma unroll
        for (int j = 0; j < 4; j++) acc[i][j] = fz;
    const F16* cb = ctxT + (size_t)b * NN * KCH;

    for (int kt = 0; kt < KCH / 32; kt++) {
        int c0 = kt * 32;
        __syncthreads();
#pragma unroll
        for (int p = 0; p < 4; p++) {
            int row = (t >> 3) + p * 32;
            int cc = (t & 7) * 4;
            float4 v = *(const float4*)&w_w[(size_t)(m0 + row) * KCH + c0 + cc];
            f16x4 h; h[0] = (F16)v.x; h[1] = (F16)v.y; h[2] = (F16)v.z; h[3] = (F16)v.w;
            *(f16x4*)&Al[row][cc] = h;
        }
#pragma unroll
        for (int p = 0; p < 2; p++) {
            int row = (t >> 2) + p * 64;
            int cc = (t & 3) * 8;
            *(int4*)&Bl[row][cc] = *(const int4*)&cb[(size_t)(n0 + row) * KCH + c0 + cc];
        }
        __syncthreads();
        f16x8 a[4];
#pragma unroll
        for (int fi = 0; fi < 4; fi++)
            a[fi] = *(f16x8*)&Al[wr * 64 + fi * 16 + lc][lr * 8];
#pragma unroll
        for (int fj = 0; fj < 4; fj++) {
            f16x8 bb = *(f16x8*)&Bl[wc * 64 + fj * 16 + lc][lr * 8];
#pragma unroll
            for (int fi = 0; fi < 4; fi++)
                acc[fi][fj] = __builtin_amdgcn_mfma_f32_16x16x32_f16(a[fi], bb, acc[fi][fj], 0, 0, 0);
        }
    }

#pragma unroll
    for (int fi = 0; fi < 4; fi++) {
        int o0 = m0 + wr * 64 + fi * 16 + lr * 4;
#pragma unroll
        for (int fj = 0; fj < 4; fj++) {
            int n = n0 + wc * 64 + fj * 16 + lc;
#pragma unroll
            for (int r = 0; r < 4; r++) {
                out[((size_t)b * OCH + o0 + r) * NN + n] = acc[fi][fj][r] + w_b[o0 + r];
            }
        }
    }
}

// ---------------------------------------------------------------- launch
extern "C" void kernel_launch(void* const* d_in, const int* in_sizes, int n_in,
                              void* d_out, int out_size, void* d_ws, size_t ws_size,
                              hipStream_t stream) {
    const float* x       = (const float*)d_in[0];
    const float* key_w   = (const float*)d_in[1];
    const float* key_b   = (const float*)d_in[2];
    const float* gamma   = (const float*)d_in[3];
    const float* beta    = (const float*)d_in[4];
    const float* mean    = (const float*)d_in[5];
    const float* var     = (const float*)d_in[6];
    const float* value_w = (const float*)d_in[7];
    const float* value_b = (const float*)d_in[8];
    const float* w_w     = (const float*)d_in[9];
    const float* w_b     = (const float*)d_in[10];
    float* out = (float*)d_out;
    char* ws = (char*)d_ws;
    F16* xT   = (F16*)(ws + XT_OFF);
    F16* KQt  = (F16*)(ws + KQT_OFF);
    F16* Vg   = (F16*)(ws + VG_OFF);
    F16* ctxT = (F16*)(ws + CTX_OFF);

    hipLaunchKernelGGL(k_transpose, dim3(8, 64, 4), dim3(256), 0, stream, x, xT);
    hipLaunchKernelGGL(k_kv_gemm, dim3(32, 4, 4), dim3(256), 0, stream,
                       xT, key_w, key_b, gamma, beta, mean, var, value_w, value_b, KQt, Vg);
    hipLaunchKernelGGL(k_flash, dim3(256), dim3(256), 0, stream, KQt, Vg, ctxT);
    hipLaunchKernelGGL(k_out_gemm, dim3(32, 4, 4), dim3(256), 0, stream, ctxT, w_w, w_b, out);
}